// Round 1
// 141.460 us; speedup vs baseline: 1.0119x; 1.0119x over previous
//
#include <hip/hip_runtime.h>
#include <hip/hip_bf16.h>
#include <math.h>

// Problem constants (B, Cin, Cmid, H, W) = (2, 256, 128, 112, 112), R=3
constexpr int B    = 2;
constexpr int CIN  = 256;
constexpr int CMID = 128;
constexpr int H    = 112;
constexpr int W    = 112;
constexpr int HW   = H * W;        // 12544
constexpr int NPIX = B * HW;       // 25088
constexpr int RAD  = 3;
constexpr int KS   = 7;
constexpr int DD   = 49;

typedef __attribute__((ext_vector_type(8))) short  short8;   // 8 bf16 (4 VGPR)
typedef __attribute__((ext_vector_type(4))) float  float4v;  // MFMA C/D

// RNE fp32-pair -> packed bf16x2 via v_cvt_pk_bf16_f32 (compiler-lowered)
__device__ __forceinline__ unsigned pkbf(float a, float b) {
    __hip_bfloat162 h = __float22bfloat162_rn(make_float2(a, b));
    union { __hip_bfloat162 h2; unsigned u; } c;
    c.h2 = h;
    return c.u;
}

// ---------------------------------------------------------------------------
// Kernel 1: q = l2norm(Wq @ phi_cur), k = l2norm(Wk @ phi_rnd)  via bf16 MFMA.
// Block = 64 pixels, all 128 outputs.  phi tile staged in LDS with COALESCED
// float4 channel-row loads, transposed during write (packed bf16 ch-pairs,
// b32 writes) into pixel-major rows.
// ROW STRIDE = 264 shorts (528 B): holds all 256 channels; 264/2 = 132 dwords
// = 4 mod 32 -> frag ds_read_b128 hits the structural 8-cycle minimum.
// W conversion f32->bf16 is FOLDED IN (cvt_pk during A-frag build; W is
// 128 KB, L2-hot) -- the separate convert_w kernel + launch gap is gone.
// Wave w owns out-channels [32w,32w+32): A-frags preloaded into registers;
// K-loop = 8 x (4 B-frag ds_reads + 8 MFMA).  Cross-wave l2norm via LDS.
// Output bf16 pixel-major.
// ---------------------------------------------------------------------------
constexpr int PSTR = 264;           // shorts per pixel row in pt

__global__ __launch_bounds__(256) void proj_mfma(
    const float* __restrict__ phi_cur, const float* __restrict__ phi_rnd,
    const float* __restrict__ Wq, const float* __restrict__ Wk,
    unsigned short* __restrict__ q_ws, unsigned short* __restrict__ k_ws)
{
    __shared__ unsigned short pt[64 * PSTR];  // 33,792 B  pixel-major bf16
    __shared__ float red[4][64];

    const int tid  = threadIdx.x;
    const int lane = tid & 63;
    const int wv   = __builtin_amdgcn_readfirstlane(tid >> 6);
    const int t    = blockIdx.y;                    // 0 -> q, 1 -> k

    const float* __restrict__ phi  = t ? phi_rnd : phi_cur;
    const float* __restrict__ Wf   = t ? Wk : Wq;
    unsigned short* __restrict__ outp = t ? k_ws : q_ws;

    const int pgb = blockIdx.x * 64;                // 64-aligned, no b crossing
    const int b   = pgb / HW;
    const int pim = pgb % HW;
    const float* pbase = phi + (size_t)b * CIN * HW + pim;

    // ---- stage phi tile: 8 passes; thread -> (channel-pair, pixel-quad) ----
#pragma unroll
    for (int pass = 0; pass < 8; ++pass) {
        const int idx = pass * 256 + tid;
        const int cp  = idx >> 4;          // channel pair 0..127
        const int pq  = idx & 15;          // pixel quad  0..15
        const int c0  = cp * 2;
        const float4 va = *(const float4*)(pbase + (size_t)c0 * HW + pq * 4);
        const float4 vb = *(const float4*)(pbase + (size_t)(c0 + 1) * HW + pq * 4);
        *(unsigned*)(pt + (pq * 4 + 0) * PSTR + c0) = pkbf(va.x, vb.x);
        *(unsigned*)(pt + (pq * 4 + 1) * PSTR + c0) = pkbf(va.y, vb.y);
        *(unsigned*)(pt + (pq * 4 + 2) * PSTR + c0) = pkbf(va.z, vb.z);
        *(unsigned*)(pt + (pq * 4 + 3) * PSTR + c0) = pkbf(va.w, vb.w);
    }

    // ---- A-frags: this wave's 32 W rows, f32 -> bf16 via cvt_pk (L2-hot) ----
    const int m = lane & 15, quad = lane >> 4;
    short8 af[2][8];
#pragma unroll
    for (int ot = 0; ot < 2; ++ot)
#pragma unroll
        for (int kc = 0; kc < 8; ++kc) {
            const float* wr = Wf + (size_t)(wv * 32 + ot * 16 + m) * CIN
                                 + kc * 32 + quad * 8;
            const float4 w0 = *(const float4*)(wr);
            const float4 w1 = *(const float4*)(wr + 4);
            union { short8 s; unsigned u[4]; } cv;
            cv.u[0] = pkbf(w0.x, w0.y);
            cv.u[1] = pkbf(w0.z, w0.w);
            cv.u[2] = pkbf(w1.x, w1.y);
            cv.u[3] = pkbf(w1.z, w1.w);
            af[ot][kc] = cv.s;
        }

    __syncthreads();

    // ---- MFMA: 2 out-tiles x 4 pixel-tiles x K=256 ----
    float4v acc[2][4];
#pragma unroll
    for (int ot = 0; ot < 2; ++ot)
#pragma unroll
        for (int nt = 0; nt < 4; ++nt) acc[ot][nt] = (float4v)0.f;

#pragma unroll
    for (int kc = 0; kc < 8; ++kc) {
        short8 bf[4];
#pragma unroll
        for (int nt = 0; nt < 4; ++nt)
            bf[nt] = *(const short8*)(pt + (nt * 16 + m) * PSTR + kc * 32 + quad * 8);
#pragma unroll
        for (int ot = 0; ot < 2; ++ot)
#pragma unroll
            for (int nt = 0; nt < 4; ++nt)
                acc[ot][nt] = __builtin_amdgcn_mfma_f32_16x16x32_bf16(
                    af[ot][kc], bf[nt], acc[ot][nt], 0, 0, 0);
    }

    // ---- per-pixel L2 norm: C layout col=lane&15=pixel, row=quad*4+reg=och
#pragma unroll
    for (int nt = 0; nt < 4; ++nt) {
        float ss = 0.f;
#pragma unroll
        for (int ot = 0; ot < 2; ++ot)
#pragma unroll
            for (int r = 0; r < 4; ++r)
                ss = fmaf(acc[ot][nt][r], acc[ot][nt][r], ss);
        ss += __shfl_xor(ss, 16, 64);
        ss += __shfl_xor(ss, 32, 64);
        if (quad == 0) red[wv][nt * 16 + m] = ss;
    }
    __syncthreads();

    float inv[4];
#pragma unroll
    for (int nt = 0; nt < 4; ++nt) {
        const int px = nt * 16 + m;
        const float tot = red[0][px] + red[1][px] + red[2][px] + red[3][px];
        inv[nt] = 1.f / fmaxf(sqrtf(tot), 1e-12f);
    }

    // ---- store bf16 pixel-major ----
#pragma unroll
    for (int nt = 0; nt < 4; ++nt)
#pragma unroll
        for (int ot = 0; ot < 2; ++ot) {
            uint2 st;
            st.x = pkbf(acc[ot][nt][0] * inv[nt], acc[ot][nt][1] * inv[nt]);
            st.y = pkbf(acc[ot][nt][2] * inv[nt], acc[ot][nt][3] * inv[nt]);
            *(uint2*)(outp + (size_t)(pgb + nt * 16 + m) * CMID
                      + wv * 32 + ot * 16 + quad * 4) = st;
        }
}

// ---------------------------------------------------------------------------
// Kernel 2: correlation via MFMA band-GEMM + Wv + geometry + softmax.
// Block = 16 pixels of one row.  Phase A: stage k-tile + q-tile in LDS.
// Phase B: 14 (row r, n-tile) groups round-robin over 4 waves; band-extract
// into cs.  Phase C1 (lane = offset d): Wv row in VGPRs, geometry, logits ->
// written to ls (4 KB, OVERLAID on dead qt region; same-wave write/read, no
// extra barrier).  Phase C2 (lane = pixel x col-quad): in-wave transposed
// softmax -- one ds_read_b128 + 3 local fmax + 4/4/4 shuffle-reduce steps
// with 4-way pixel ILP, replacing 96 dependent shuffle steps per wave.
// 2 barriers per block total.
// ---------------------------------------------------------------------------
constexpr int TILE = 16;
constexpr int COLS = TILE + 6;      // 22
constexpr int NV   = KS * COLS;     // 154 staged pixel-vectors
constexpr int KSTR = 136;           // shorts per vector in LDS (272 B)

__global__ __launch_bounds__(256) void corr_kernel(
    const unsigned short* __restrict__ q_ws, const unsigned short* __restrict__ k_ws,
    const float* __restrict__ P_cur, const float* __restrict__ P_rnd,
    const float* __restrict__ Wvm, const float* __restrict__ bv,
    const float* __restrict__ gamma_p, float* __restrict__ out)
{
    __shared__ unsigned short kt[NV * KSTR];                 // 41,888 B
    __shared__ alignas(16) unsigned short qt[TILE * KSTR];   //  4,352 B (ls overlay)
    __shared__ float cs[TILE][52];                           //  3,328 B corr vectors

    const int tid  = threadIdx.x;
    const int lane = tid & 63;
    const int wv   = __builtin_amdgcn_readfirstlane(tid >> 6);
    const int w0   = blockIdx.x * TILE;
    const int h    = blockIdx.y;
    const int b    = blockIdx.z;

    // ---- phase A: stage k-tile + q-tile (coalesced dwordx4; OOB zeros) ----
    const int sub  = tid & 15;
    const int vgrp = tid >> 4;          // 0..15
#pragma unroll
    for (int pass = 0; pass < 10; ++pass) {
        const int vi = pass * 16 + vgrp;
        if (vi < NV) {
            const int rr = vi / COLS;
            const int cc = vi % COLS;
            const int hh = h + rr - RAD;
            const int ww = w0 + cc - RAD;
            uint4 v = make_uint4(0, 0, 0, 0);
            if (hh >= 0 && hh < H && ww >= 0 && ww < W)
                v = *(const uint4*)(k_ws + (size_t)(b * HW + hh * W + ww) * CMID + sub * 8);
            *(uint4*)(kt + vi * KSTR + sub * 8) = v;
        }
    }
    {
        const uint4 v = *(const uint4*)(q_ws + (size_t)(b * HW + h * W + w0 + vgrp) * CMID + sub * 8);
        *(uint4*)(qt + vgrp * KSTR + sub * 8) = v;
    }

    // ---- per-lane constants for phase C (loads overlap staging) ----
    const int  ld    = (lane < DD) ? lane : 0;
    const bool valid = (lane < DD);
    float wrow[52];
#pragma unroll
    for (int e = 0; e < DD; ++e) wrow[e] = Wvm[ld * DD + e];
    wrow[49] = wrow[50] = wrow[51] = 0.f;
    const float bvv   = bv[ld];
    const float gamma = gamma_p[0];

    __syncthreads();

    // zero the cs padding (cols 49..51) so phase C1's 0*pad stays 0
    if (tid < TILE * 3)
        cs[tid / 3][49 + tid % 3] = 0.f;

    // ---- phase B: MFMA band-GEMM ----
    const int m = lane & 15, quad = lane >> 4;
    for (int g = wv; g < 14; g += 4) {
        const int r  = g >> 1;
        const int nt = g & 1;
        const int vi = min(r * COLS + nt * 16 + m, NV - 1);  // clamp OOB cols
        float4v acc = (float4v)0.f;
#pragma unroll
        for (int kc = 0; kc < 4; ++kc) {
            const short8 afrag = *(const short8*)(qt + m * KSTR + kc * 32 + quad * 8);
            const short8 bfrag = *(const short8*)(kt + vi * KSTR + kc * 32 + quad * 8);
            acc = __builtin_amdgcn_mfma_f32_16x16x32_bf16(afrag, bfrag, acc, 0, 0, 0);
        }
        // band extract: D row = pixel = quad*4+reg, col cc = nt*16 + m
#pragma unroll
        for (int reg = 0; reg < 4; ++reg) {
            const int p   = quad * 4 + reg;
            const int off = nt * 16 + m - p;     // dx + RAD
            if (off >= 0 && off <= 6)
                cs[p][r * 7 + off] = acc[reg];
        }
    }
    __syncthreads();
    // qt is dead from here on -> overlay ls (16 rows x 64 f32 = 4,096 B)
    float* lsf = reinterpret_cast<float*>(qt);

    // ---- phase C1: geometry + logits (lane = d); write logit rows to ls ----
    const int dy = ld / KS - RAD;
    const int dx = ld % KS - RAD;

#pragma unroll
    for (int i = 0; i < 4; ++i) {
        const int pl = wv * 4 + i;      // pixel local 0..15

        const int hn = h + dy, wn = w0 + pl + dx;
        const bool inb = valid && hn >= 0 && hn < H && wn >= 0 && wn < W;
        const float* pc = P_cur + (size_t)b * 3 * HW + (h * W + w0 + pl);
        const float cx = pc[0], cy = pc[HW], cz = pc[2 * HW];
        float rx = 0.f, ry = 0.f, rz = 0.f;
        if (inb) {
            const float* pr = P_rnd + (size_t)b * 3 * HW + (hn * W + wn);
            rx = pr[0]; ry = pr[HW]; rz = pr[2 * HW];
        }
        const float dpx = cx - rx, dpy = cy - ry, dpz = cz - rz;
        const float dist = sqrtf(fmaxf(dpx * dpx + dpy * dpy + dpz * dpz, 1e-12f));

        float logit = -INFINITY;
        if (valid) {
            float v = bvv;
#pragma unroll
            for (int e4 = 0; e4 < 13; ++e4) {
                const float4 c4 = *(const float4*)&cs[pl][e4 * 4];
                v = fmaf(wrow[e4 * 4 + 0], c4.x, v);
                v = fmaf(wrow[e4 * 4 + 1], c4.y, v);
                v = fmaf(wrow[e4 * 4 + 2], c4.z, v);
                v = fmaf(wrow[e4 * 4 + 3], c4.w, v);
            }
            logit = v + gamma * (-dist - 0.5f * fabsf(dpz));
        }
        lsf[pl * 64 + lane] = logit;    // lanes 49..63 store -inf
    }

    // ---- phase C2: transposed in-wave softmax (lane = pixel x col-quad) ----
    // Same-wave LDS write->read: compiler-ordered via lgkmcnt, no barrier.
    {
        const int pli = lane >> 4;      // 0..3 within wave
        const int dq  = lane & 15;      // column quad (cols dq*4 .. dq*4+3)
        const int pl  = wv * 4 + pli;

        const float4 v = ((const float4*)lsf)[pl * 16 + dq];

        float m4 = fmaxf(fmaxf(v.x, v.y), fmaxf(v.z, v.w));
#pragma unroll
        for (int s = 1; s < 16; s <<= 1)
            m4 = fmaxf(m4, __shfl_xor(m4, s, 64));

        const float e0 = __expf(v.x - m4);
        const float e1 = __expf(v.y - m4);
        const float e2 = __expf(v.z - m4);
        const float e3 = __expf(v.w - m4);
        float Z = (e0 + e1) + (e2 + e3);

        // dx = col%7-3, dy = col/7-3  (cols >= 49 have e == 0, values moot)
        const int c0i = dq * 4;
        float dus = 0.f, dvs = 0.f;
        {
            const float ex[4] = { e0, e1, e2, e3 };
#pragma unroll
            for (int j = 0; j < 4; ++j) {
                const int col = c0i + j;
                dus = fmaf(ex[j], (float)(col % KS - RAD), dus);
                dvs = fmaf(ex[j], (float)(col / KS - RAD), dvs);
            }
        }
#pragma unroll
        for (int s = 1; s < 16; s <<= 1) {
            Z   += __shfl_xor(Z,   s, 64);
            dus += __shfl_xor(dus, s, 64);
            dvs += __shfl_xor(dvs, s, 64);
        }

        if (dq == 0) {
            const int pg = b * HW + h * W + w0 + pl;
            const float invZ = 1.f / Z;
            out[pg]            = dus * invZ;
            out[NPIX + pg]     = dvs * invZ;
            out[2 * NPIX + pg] = invZ;       // conf = max w = exp(lmax-lmax)/Z
        }
    }
}

// ---------------------------------------------------------------------------
extern "C" void kernel_launch(void* const* d_in, const int* in_sizes, int n_in,
                              void* d_out, int out_size, void* d_ws, size_t ws_size,
                              hipStream_t stream)
{
    const float* phi_cur = (const float*)d_in[0];
    const float* phi_rnd = (const float*)d_in[1];
    const float* P_cur   = (const float*)d_in[2];
    const float* P_rnd   = (const float*)d_in[3];
    const float* Wq      = (const float*)d_in[4];
    const float* Wk      = (const float*)d_in[5];
    const float* Wv      = (const float*)d_in[6];
    const float* bv      = (const float*)d_in[7];
    const float* gm      = (const float*)d_in[8];
    float* out = (float*)d_out;

    unsigned short* ws   = (unsigned short*)d_ws;
    unsigned short* q_ws = ws;                                  // NPIX*CMID bf16
    unsigned short* k_ws = q_ws + (size_t)NPIX * CMID;          // NPIX*CMID bf16

    proj_mfma<<<dim3(NPIX / 64, 2), 256, 0, stream>>>(
        phi_cur, phi_rnd, Wq, Wk, q_ws, k_ws);

    corr_kernel<<<dim3(W / TILE, H, B), 256, 0, stream>>>(
        q_ws, k_ws, P_cur, P_rnd, Wv, bv, gm, out);
}

// Round 2
// 138.361 us; speedup vs baseline: 1.0346x; 1.0224x over previous
//
#include <hip/hip_runtime.h>
#include <hip/hip_bf16.h>
#include <math.h>

// Problem constants (B, Cin, Cmid, H, W) = (2, 256, 128, 112, 112), R=3
constexpr int B    = 2;
constexpr int CIN  = 256;
constexpr int CMID = 128;
constexpr int H    = 112;
constexpr int W    = 112;
constexpr int HW   = H * W;        // 12544
constexpr int NPIX = B * HW;       // 25088
constexpr int RAD  = 3;
constexpr int KS   = 7;
constexpr int DD   = 49;

typedef __attribute__((ext_vector_type(8))) short  short8;   // 8 bf16 (4 VGPR)
typedef __attribute__((ext_vector_type(4))) float  float4v;  // MFMA C/D

// RNE fp32-pair -> packed bf16x2 via v_cvt_pk_bf16_f32 (compiler-lowered)
__device__ __forceinline__ unsigned pkbf(float a, float b) {
    __hip_bfloat162 h = __float22bfloat162_rn(make_float2(a, b));
    union { __hip_bfloat162 h2; unsigned u; } c;
    c.h2 = h;
    return c.u;
}

// ---------------------------------------------------------------------------
// Kernel 0 (prep, tiny): Wq/Wk f32 -> bf16; Wv f32 -> padded f32 [49][52]
// (52-float rows, 208 B, 16B-aligned -> corr loads 13 x b128 instead of 49
// scalar dwords per thread).
// ---------------------------------------------------------------------------
__global__ __launch_bounds__(256) void prep(
    const float* __restrict__ Wq, const float* __restrict__ Wk,
    const float* __restrict__ Wv,
    unsigned short* __restrict__ wqb, unsigned short* __restrict__ wkb,
    float* __restrict__ wvp)
{
    if (blockIdx.x < 64) {
        const int i  = blockIdx.x * 256 + threadIdx.x;   // float4 index
        const int n4 = (CMID * CIN) / 4;                 // 8192 per matrix
        const float4 v = (i < n4) ? ((const float4*)Wq)[i] : ((const float4*)Wk)[i - n4];
        uint2 r;
        r.x = pkbf(v.x, v.y);
        r.y = pkbf(v.z, v.w);
        if (i < n4) ((uint2*)wqb)[i] = r;
        else        ((uint2*)wkb)[i - n4] = r;
    } else {
        for (int idx = threadIdx.x; idx < DD * 52; idx += 256) {
            const int r = idx / 52, c = idx % 52;
            wvp[idx] = (c < DD) ? Wv[r * DD + c] : 0.f;
        }
    }
}

// ---------------------------------------------------------------------------
// Kernel 1: q = l2norm(Wq @ phi_cur), k = l2norm(Wk @ phi_rnd)  via bf16 MFMA.
// Block = 64 pixels, all 128 outputs.  phi tile staged in LDS (coalesced
// float4 channel-row loads, transposed to pixel-major bf16 on write).
// ROW STRIDE = 264 shorts; column XOR-SWIZZLE by ((pix>>3)&3)<<3 (shorts):
// derived bank map -> staging b32 writes go 8-way -> 2-way (free, m136);
// frag b128 reads stay at the 8-round structural optimum.
// A-frags are loaded per-kc inside the K-loop from prep'd bf16 W (L2-hot):
// frees ~56 VGPR vs preloading af[2][8]; __launch_bounds__(256,4) caps VGPR
// at 128 -> 4 blocks/CU (LDS 4x34.8KB=139KB fits) -> all 784 blocks resident.
// ---------------------------------------------------------------------------
constexpr int PSTR = 264;           // shorts per pixel row in pt

__global__ __launch_bounds__(256, 4) void proj_mfma(
    const float* __restrict__ phi_cur, const float* __restrict__ phi_rnd,
    const unsigned short* __restrict__ wq_bf, const unsigned short* __restrict__ wk_bf,
    unsigned short* __restrict__ q_ws, unsigned short* __restrict__ k_ws)
{
    __shared__ unsigned short pt[64 * PSTR];  // 33,792 B  pixel-major bf16
    __shared__ float red[4][64];

    const int tid  = threadIdx.x;
    const int lane = tid & 63;
    const int wv   = __builtin_amdgcn_readfirstlane(tid >> 6);
    const int t    = blockIdx.y;                    // 0 -> q, 1 -> k

    const float* __restrict__ phi          = t ? phi_rnd : phi_cur;
    const unsigned short* __restrict__ Wbf = t ? wk_bf : wq_bf;
    unsigned short* __restrict__ outp      = t ? k_ws : q_ws;

    const int pgb = blockIdx.x * 64;                // 64-aligned, no b crossing
    const int b   = pgb / HW;
    const int pim = pgb % HW;
    const float* pbase = phi + (size_t)b * CIN * HW + pim;

    // ---- stage phi tile: 8 passes; thread -> (channel-pair, pixel-quad) ----
#pragma unroll
    for (int pass = 0; pass < 8; ++pass) {
        const int idx = pass * 256 + tid;
        const int cp  = idx >> 4;          // channel pair 0..127
        const int pq  = idx & 15;          // pixel quad  0..15
        const int c0  = cp * 2;
        const int swz = ((pq >> 1) & 3) << 3;        // == ((pix>>3)&3)<<3
        const float4 va = *(const float4*)(pbase + (size_t)c0 * HW + pq * 4);
        const float4 vb = *(const float4*)(pbase + (size_t)(c0 + 1) * HW + pq * 4);
        const int col = c0 ^ swz;
        *(unsigned*)(pt + (pq * 4 + 0) * PSTR + col) = pkbf(va.x, vb.x);
        *(unsigned*)(pt + (pq * 4 + 1) * PSTR + col) = pkbf(va.y, vb.y);
        *(unsigned*)(pt + (pq * 4 + 2) * PSTR + col) = pkbf(va.z, vb.z);
        *(unsigned*)(pt + (pq * 4 + 3) * PSTR + col) = pkbf(va.w, vb.w);
    }

    __syncthreads();

    // ---- MFMA: 2 out-tiles x 4 pixel-tiles x K=256; A-frags per-kc ----
    const int m = lane & 15, quad = lane >> 4;
    float4v acc[2][4];
#pragma unroll
    for (int ot = 0; ot < 2; ++ot)
#pragma unroll
        for (int nt = 0; nt < 4; ++nt) acc[ot][nt] = (float4v)0.f;

#pragma unroll
    for (int kc = 0; kc < 8; ++kc) {
        const short8 af0 = *(const short8*)(Wbf +
            (size_t)(wv * 32 + m) * CIN + kc * 32 + quad * 8);
        const short8 af1 = *(const short8*)(Wbf +
            (size_t)(wv * 32 + 16 + m) * CIN + kc * 32 + quad * 8);
        short8 bfr[4];
#pragma unroll
        for (int nt = 0; nt < 4; ++nt) {
            const int row = nt * 16 + m;
            const int col = (kc * 32 + quad * 8) ^ (((row >> 3) & 3) << 3);
            bfr[nt] = *(const short8*)(pt + row * PSTR + col);
        }
#pragma unroll
        for (int nt = 0; nt < 4; ++nt) {
            acc[0][nt] = __builtin_amdgcn_mfma_f32_16x16x32_bf16(af0, bfr[nt], acc[0][nt], 0, 0, 0);
            acc[1][nt] = __builtin_amdgcn_mfma_f32_16x16x32_bf16(af1, bfr[nt], acc[1][nt], 0, 0, 0);
        }
    }

    // ---- per-pixel L2 norm: C layout col=lane&15=pixel, row=quad*4+reg=och
#pragma unroll
    for (int nt = 0; nt < 4; ++nt) {
        float ss = 0.f;
#pragma unroll
        for (int ot = 0; ot < 2; ++ot)
#pragma unroll
            for (int r = 0; r < 4; ++r)
                ss = fmaf(acc[ot][nt][r], acc[ot][nt][r], ss);
        ss += __shfl_xor(ss, 16, 64);
        ss += __shfl_xor(ss, 32, 64);
        if (quad == 0) red[wv][nt * 16 + m] = ss;
    }
    __syncthreads();

    float inv[4];
#pragma unroll
    for (int nt = 0; nt < 4; ++nt) {
        const int px = nt * 16 + m;
        const float tot = red[0][px] + red[1][px] + red[2][px] + red[3][px];
        inv[nt] = 1.f / fmaxf(sqrtf(tot), 1e-12f);
    }

    // ---- store bf16 pixel-major ----
#pragma unroll
    for (int nt = 0; nt < 4; ++nt)
#pragma unroll
        for (int ot = 0; ot < 2; ++ot) {
            uint2 st;
            st.x = pkbf(acc[ot][nt][0] * inv[nt], acc[ot][nt][1] * inv[nt]);
            st.y = pkbf(acc[ot][nt][2] * inv[nt], acc[ot][nt][3] * inv[nt]);
            *(uint2*)(outp + (size_t)(pgb + nt * 16 + m) * CMID
                      + wv * 32 + ot * 16 + quad * 4) = st;
        }
}

// ---------------------------------------------------------------------------
// Kernel 2: correlation via MFMA band-GEMM + Wv + geometry + softmax.
// Block = 16 pixels of one row.  XCD-chunked block swizzle (1568 = 8*196,
// bijective): each XCD gets a contiguous band of rows -> k-halo re-reads
// (5x overlap) hit the per-XCD L2 instead of refetching HBM.
// Phase A: stage k-tile + q-tile.  Phase B: 14 groups round-robin over 4
// waves, band-extract into cs.  Phase C1 (lane = d): Wv row via 13 x b128
// from padded wvp (was 49 scalar loads), dual-chain dot, logits -> ls
// (overlaid on dead qt; same-wave, no barrier).  Phase C2: transposed
// in-wave softmax.  2 barriers per block total.
// ---------------------------------------------------------------------------
constexpr int TILE = 16;
constexpr int COLS = TILE + 6;      // 22
constexpr int NV   = KS * COLS;     // 154 staged pixel-vectors
constexpr int KSTR = 136;           // shorts per vector in LDS (272 B)

__global__ __launch_bounds__(256) void corr_kernel(
    const unsigned short* __restrict__ q_ws, const unsigned short* __restrict__ k_ws,
    const float* __restrict__ P_cur, const float* __restrict__ P_rnd,
    const float* __restrict__ wvp, const float* __restrict__ bv,
    const float* __restrict__ gamma_p, float* __restrict__ out)
{
    __shared__ unsigned short kt[NV * KSTR];                 // 41,888 B
    __shared__ alignas(16) unsigned short qt[TILE * KSTR];   //  4,352 B (ls overlay)
    __shared__ float cs[TILE][52];                           //  3,328 B corr vectors

    const int tid  = threadIdx.x;
    const int lane = tid & 63;
    const int wv   = __builtin_amdgcn_readfirstlane(tid >> 6);

    // ---- XCD-chunked bijective swizzle: fid -> contiguous 196-block chunk --
    const int fid = (blockIdx.z * H + blockIdx.y) * (W / TILE) + blockIdx.x;
    const int swz = (fid & 7) * 196 + (fid >> 3);
    const int b   = swz / (H * (W / TILE));
    const int rem = swz % (H * (W / TILE));
    const int h   = rem / (W / TILE);
    const int w0  = (rem % (W / TILE)) * TILE;

    // ---- phase A: stage k-tile + q-tile (coalesced dwordx4; OOB zeros) ----
    const int sub  = tid & 15;
    const int vgrp = tid >> 4;          // 0..15
#pragma unroll
    for (int pass = 0; pass < 10; ++pass) {
        const int vi = pass * 16 + vgrp;
        if (vi < NV) {
            const int rr = vi / COLS;
            const int cc = vi % COLS;
            const int hh = h + rr - RAD;
            const int ww = w0 + cc - RAD;
            uint4 v = make_uint4(0, 0, 0, 0);
            if (hh >= 0 && hh < H && ww >= 0 && ww < W)
                v = *(const uint4*)(k_ws + (size_t)(b * HW + hh * W + ww) * CMID + sub * 8);
            *(uint4*)(kt + vi * KSTR + sub * 8) = v;
        }
    }
    {
        const uint4 v = *(const uint4*)(q_ws + (size_t)(b * HW + h * W + w0 + vgrp) * CMID + sub * 8);
        *(uint4*)(qt + vgrp * KSTR + sub * 8) = v;
    }

    // ---- per-lane constants for phase C (loads overlap staging) ----
    const int  ld    = (lane < DD) ? lane : 0;
    const bool valid = (lane < DD);
    float4 wq4[13];
#pragma unroll
    for (int j = 0; j < 13; ++j)
        wq4[j] = *(const float4*)(wvp + ld * 52 + j * 4);
    const float bvv   = bv[ld];
    const float gamma = gamma_p[0];

    __syncthreads();

    // zero the cs padding (cols 49..51) so phase C1's 0*pad stays 0
    if (tid < TILE * 3)
        cs[tid / 3][49 + tid % 3] = 0.f;

    // ---- phase B: MFMA band-GEMM ----
    const int m = lane & 15, quad = lane >> 4;
    for (int g = wv; g < 14; g += 4) {
        const int r  = g >> 1;
        const int nt = g & 1;
        const int vi = min(r * COLS + nt * 16 + m, NV - 1);  // clamp OOB cols
        float4v acc = (float4v)0.f;
#pragma unroll
        for (int kc = 0; kc < 4; ++kc) {
            const short8 afrag = *(const short8*)(qt + m * KSTR + kc * 32 + quad * 8);
            const short8 bfrag = *(const short8*)(kt + vi * KSTR + kc * 32 + quad * 8);
            acc = __builtin_amdgcn_mfma_f32_16x16x32_bf16(afrag, bfrag, acc, 0, 0, 0);
        }
        // band extract: D row = pixel = quad*4+reg, col cc = nt*16 + m
#pragma unroll
        for (int reg = 0; reg < 4; ++reg) {
            const int p   = quad * 4 + reg;
            const int off = nt * 16 + m - p;     // dx + RAD
            if (off >= 0 && off <= 6)
                cs[p][r * 7 + off] = acc[reg];
        }
    }
    __syncthreads();
    // qt is dead from here on -> overlay ls (16 rows x 64 f32 = 4,096 B)
    float* lsf = reinterpret_cast<float*>(qt);

    // ---- phase C1: geometry + logits (lane = d); write logit rows to ls ----
    const int dy = ld / KS - RAD;
    const int dx = ld % KS - RAD;

#pragma unroll
    for (int i = 0; i < 4; ++i) {
        const int pl = wv * 4 + i;      // pixel local 0..15

        const int hn = h + dy, wn = w0 + pl + dx;
        const bool inb = valid && hn >= 0 && hn < H && wn >= 0 && wn < W;
        const float* pc = P_cur + (size_t)b * 3 * HW + (h * W + w0 + pl);
        const float cx = pc[0], cy = pc[HW], cz = pc[2 * HW];
        float rx = 0.f, ry = 0.f, rz = 0.f;
        if (inb) {
            const float* pr = P_rnd + (size_t)b * 3 * HW + (hn * W + wn);
            rx = pr[0]; ry = pr[HW]; rz = pr[2 * HW];
        }
        const float dpx = cx - rx, dpy = cy - ry, dpz = cz - rz;
        const float dist = sqrtf(fmaxf(dpx * dpx + dpy * dpy + dpz * dpz, 1e-12f));

        float logit = -INFINITY;
        if (valid) {
            float va0 = bvv, va1 = 0.f;     // dual independent FMA chains
#pragma unroll
            for (int e4 = 0; e4 < 13; ++e4) {
                const float4 c4 = *(const float4*)&cs[pl][e4 * 4];
                const float4 w4 = wq4[e4];
                if (e4 & 1) {
                    va1 = fmaf(w4.x, c4.x, va1);
                    va1 = fmaf(w4.y, c4.y, va1);
                    va1 = fmaf(w4.z, c4.z, va1);
                    va1 = fmaf(w4.w, c4.w, va1);
                } else {
                    va0 = fmaf(w4.x, c4.x, va0);
                    va0 = fmaf(w4.y, c4.y, va0);
                    va0 = fmaf(w4.z, c4.z, va0);
                    va0 = fmaf(w4.w, c4.w, va0);
                }
            }
            logit = (va0 + va1) + gamma * (-dist - 0.5f * fabsf(dpz));
        }
        lsf[pl * 64 + lane] = logit;    // lanes 49..63 store -inf
    }

    // ---- phase C2: transposed in-wave softmax (lane = pixel x col-quad) ----
    // Same-wave LDS write->read: compiler-ordered via lgkmcnt, no barrier.
    {
        const int pli = lane >> 4;      // 0..3 within wave
        const int dq  = lane & 15;      // column quad (cols dq*4 .. dq*4+3)
        const int pl  = wv * 4 + pli;

        const float4 v = ((const float4*)lsf)[pl * 16 + dq];

        float m4 = fmaxf(fmaxf(v.x, v.y), fmaxf(v.z, v.w));
#pragma unroll
        for (int s = 1; s < 16; s <<= 1)
            m4 = fmaxf(m4, __shfl_xor(m4, s, 64));

        const float e0 = __expf(v.x - m4);
        const float e1 = __expf(v.y - m4);
        const float e2 = __expf(v.z - m4);
        const float e3 = __expf(v.w - m4);
        float Z = (e0 + e1) + (e2 + e3);

        // dx = col%7-3, dy = col/7-3  (cols >= 49 have e == 0, values moot)
        const int c0i = dq * 4;
        float dus = 0.f, dvs = 0.f;
        {
            const float ex[4] = { e0, e1, e2, e3 };
#pragma unroll
            for (int j = 0; j < 4; ++j) {
                const int col = c0i + j;
                dus = fmaf(ex[j], (float)(col % KS - RAD), dus);
                dvs = fmaf(ex[j], (float)(col / KS - RAD), dvs);
            }
        }
#pragma unroll
        for (int s = 1; s < 16; s <<= 1) {
            Z   += __shfl_xor(Z,   s, 64);
            dus += __shfl_xor(dus, s, 64);
            dvs += __shfl_xor(dvs, s, 64);
        }

        if (dq == 0) {
            const int pg = b * HW + h * W + w0 + pl;
            const float invZ = 1.f / Z;
            out[pg]            = dus * invZ;
            out[NPIX + pg]     = dvs * invZ;
            out[2 * NPIX + pg] = invZ;       // conf = max w = exp(lmax-lmax)/Z
        }
    }
}

// ---------------------------------------------------------------------------
extern "C" void kernel_launch(void* const* d_in, const int* in_sizes, int n_in,
                              void* d_out, int out_size, void* d_ws, size_t ws_size,
                              hipStream_t stream)
{
    const float* phi_cur = (const float*)d_in[0];
    const float* phi_rnd = (const float*)d_in[1];
    const float* P_cur   = (const float*)d_in[2];
    const float* P_rnd   = (const float*)d_in[3];
    const float* Wq      = (const float*)d_in[4];
    const float* Wk      = (const float*)d_in[5];
    const float* Wv      = (const float*)d_in[6];
    const float* bv      = (const float*)d_in[7];
    const float* gm      = (const float*)d_in[8];
    float* out = (float*)d_out;

    unsigned short* ws   = (unsigned short*)d_ws;
    unsigned short* q_ws = ws;                                  // NPIX*CMID bf16
    unsigned short* k_ws = q_ws + (size_t)NPIX * CMID;          // NPIX*CMID bf16
    unsigned short* wqb  = k_ws + (size_t)NPIX * CMID;          // CMID*CIN bf16
    unsigned short* wkb  = wqb + (size_t)CMID * CIN;
    float*          wvp  = (float*)(wkb + (size_t)CMID * CIN);  // 49x52 f32 (16B-aligned)

    prep<<<dim3(65), 256, 0, stream>>>(Wq, Wk, Wv, wqb, wkb, wvp);

    proj_mfma<<<dim3(NPIX / 64, 2), 256, 0, stream>>>(
        phi_cur, phi_rnd, wqb, wkb, q_ws, k_ws);

    corr_kernel<<<dim3(W / TILE, H, B), 256, 0, stream>>>(
        q_ws, k_ws, P_cur, P_rnd, wvp, bv, gm, out);
}